// Round 7
// baseline (1348.071 us; speedup 1.0000x reference)
//
#include <hip/hip_runtime.h>

// Problem constants
#define BB   512
#define CC   22
#define TT   1000
#define HH   64
#define NCLS 4
#define TC   200          // x chunk steps staged in LDS
#define NCHUNK (TT / TC)
#define RING 40           // h ring steps (1000 % 40 == 0)

typedef _Float16 f16;
typedef __attribute__((ext_vector_type(8))) _Float16 f16x8;
typedef __attribute__((ext_vector_type(4))) float    f32x4;

union F8U { f16x8 v; uint4 u; f16 h[8]; };

__device__ __forceinline__ float sigm(float x) { return 1.0f / (1.0f + __expf(-x)); }
__device__ __forceinline__ float tanh_(float x) {
    float e = __expf(-2.0f * fabsf(x));   // (0,1], no overflow
    float r = (1.0f - e) / (1.0f + e);
    return copysignf(r, x);
}

// One wave per batch row, zero barriers. Per step:
//   P^T[16 x 256] = A(16x96) * B(96x256),  A = [h;x] replicated rows (broadcast
//   LDS reads), B = W^T RESIDENT IN AGPRs (192 regs) — MFMA reads AGPRs in
//   place, killing the 172 v_accvgpr_read/step the fdot2 design paid (R6
//   post-mortem: VGPR_Count=132 << weight footprint across all variants).
// C/D layout (col=lane&15, rows duplicated) puts ALL 4 gates of hids
// {c,c+16,c+32,c+48} in one lane -> lane-local cell update, no redistribution.
// h goes to an LDS ring (in-wave publish), dumped to global every RING steps;
// FC+softmax runs as a second, trivially memory-bound kernel.
__global__
__attribute__((amdgpu_flat_work_group_size(64, 64), amdgpu_waves_per_eu(1, 1)))
void lstm_mfma1(
    const float* __restrict__ x,     // [B, C, T]
    const float* __restrict__ W_ih,  // [4H, C]
    const float* __restrict__ W_hh,  // [4H, H]
    const float* __restrict__ b_ih,  // [4H]
    const float* __restrict__ b_hh,  // [4H]
    f16* __restrict__ hglob)         // [B, T*H] workspace
{
    __shared__ __align__(16) f16 xs[TC * 32];      // 12.8 KB: x chunk, A-layout rows
    __shared__ __align__(16) f16 hring[RING * HH]; // 5.12 KB: h ring

    const int lane = threadIdx.x;
    const int q    = lane >> 4;     // k-subblock within frag
    const int c    = lane & 15;     // B col within tile / C col
    const int r    = blockIdx.x;    // batch row

    // ---- one-time: B fragments (weights, -> AGPRs) + bias scalars ----
    // Bw{kt}[n][j] = W[16n+c][32*kt + 8q + j]; kt=0,1 from W_hh, kt=2 from W_ih
    f16x8 Bw0[16], Bw1[16], Bw2[16];
    float bias_s[16];               // bias of gate 16n+c
    #pragma unroll
    for (int n = 0; n < 16; ++n) {
        const int g = 16 * n + c;   // gate row
        F8U a, b, cc;
        const float* wr = W_hh + g * HH + 8 * q;
        #pragma unroll
        for (int j = 0; j < 8; ++j) { a.h[j] = (f16)wr[j]; b.h[j] = (f16)wr[32 + j]; }
        #pragma unroll
        for (int j = 0; j < 8; ++j) {
            const int k = 8 * q + j;
            cc.h[j] = (k < CC) ? (f16)W_ih[g * CC + k] : (f16)0.f;
        }
        Bw0[n] = a.v; Bw1[n] = b.v; Bw2[n] = cc.v;
        bias_s[n] = b_ih[g] + b_hh[g];
    }

    // h(-1) = 0 in ring slot RING-1
    if (lane < 16) {
        #pragma unroll
        for (int j = 0; j < 4; ++j) hring[(RING - 1) * HH + 16 * j + c] = (f16)0.f;
    }
    float cst[4] = {0.f, 0.f, 0.f, 0.f};   // cell state for hids 16j+c (dup'd over q)
    const float* xrow = x + (size_t)r * (CC * TT);
    f16* hout = hglob + (size_t)r * (TT * HH);
    int sprev = RING - 1, scur = 0;

    for (int chunk = 0; chunk < NCHUNK; ++chunk) {
        // ---- stage x chunk in A-frag row layout: xs[t][k], k<32 (22 real) ----
        for (int t0 = 0; t0 < TC; t0 += 64) {
            const int t = t0 + lane;
            if (t < TC) {
                const float* gx = xrow + chunk * TC + t;   // channel stride TT
                F8U u[4];
                #pragma unroll
                for (int k = 0; k < 32; ++k)
                    u[k >> 3].h[k & 7] = (k < CC) ? (f16)gx[k * TT] : (f16)0.f;
                uint4* dst = (uint4*)&xs[t * 32];
                dst[0] = u[0].u; dst[1] = u[1].u; dst[2] = u[2].u; dst[3] = u[3].u;
            }
        }
        // no barrier: single-wave block, DS ops in-order

        for (int tt = 0; tt < TC; ++tt) {
            // A-frags: x (this step) and h (prev step, ring)
            F8U Ax;  Ax.u  = *(const uint4*)&xs[tt * 32 + 8 * q];
            F8U Ah0; Ah0.u = *(const uint4*)&hring[sprev * HH + 8 * q];
            F8U Ah1; Ah1.u = *(const uint4*)&hring[sprev * HH + 32 + 8 * q];

            const f32x4 z = {0.f, 0.f, 0.f, 0.f};
            f32x4 acc[16];
            #pragma unroll
            for (int n = 0; n < 16; ++n)
                acc[n] = __builtin_amdgcn_mfma_f32_16x16x32_f16(Ax.v, Bw2[n], z, 0, 0, 0);
            #pragma unroll
            for (int n = 0; n < 16; ++n)
                acc[n] = __builtin_amdgcn_mfma_f32_16x16x32_f16(Ah0.v, Bw0[n], acc[n], 0, 0, 0);
            #pragma unroll
            for (int n = 0; n < 16; ++n)
                acc[n] = __builtin_amdgcn_mfma_f32_16x16x32_f16(Ah1.v, Bw1[n], acc[n], 0, 0, 0);

            // ---- epilogue: 4 lane-local cell updates (dup'd across q-groups) ----
            // gate G of hid 16j+c lives in acc[4G+j][0]
            #pragma unroll
            for (int j = 0; j < 4; ++j) {
                float iv = sigm (acc[j][0]      + bias_s[j]);
                float fv = sigm (acc[4 + j][0]  + bias_s[4 + j]);
                float gv = tanh_(acc[8 + j][0]  + bias_s[8 + j]);
                float ov = sigm (acc[12 + j][0] + bias_s[12 + j]);
                cst[j] = fv * cst[j] + iv * gv;
                float h = ov * tanh_(cst[j]);
                if (lane < 16) hring[scur * HH + 16 * j + c] = (f16)h;
            }

            // ---- ring dump every RING steps (coalesced, off critical path) ----
            if (scur == RING - 1) {
                const int t0g = chunk * TC + tt - (RING - 1);
                #pragma unroll
                for (int j = 0; j < 5; ++j) {
                    uint4 v = *(const uint4*)&hring[512 * j + 8 * lane];
                    *(uint4*)&hout[(size_t)t0g * HH + 512 * j + 8 * lane] = v;
                }
            }
            sprev = scur;
            scur  = (scur + 1 == RING) ? 0 : scur + 1;
        }
    }
}

// FC + softmax: logits[B][4] = h_all[B][64000] . W_fc^T + b_fc, then softmax.
// 128 blocks x 4 waves; wave = one batch row. W_fc (1 MB) is L3-resident.
__global__ __launch_bounds__(256) void fc_softmax(
    const f16*  __restrict__ hglob,  // [B, T*H]
    const float* __restrict__ W_fc,  // [NCLS, T*H]
    const float* __restrict__ b_fc,  // [NCLS]
    float* __restrict__ out)         // [B, NCLS]
{
    const int w    = threadIdx.x >> 6;
    const int lane = threadIdx.x & 63;
    const int r    = blockIdx.x * 4 + w;

    const f16* hr = hglob + (size_t)r * (TT * HH);
    float a0 = 0.f, a1 = 0.f, a2 = 0.f, a3 = 0.f;

    for (int i = 0; i < (TT * HH) / 512; ++i) {     // 125 iters
        const int k = i * 512 + lane * 8;
        F8U hv; hv.u = *(const uint4*)&hr[k];
        float hf[8];
        #pragma unroll
        for (int j = 0; j < 8; ++j) hf[j] = (float)hv.h[j];

        const float* w0 = W_fc + 0 * (TT * HH) + k;
        const float* w1 = W_fc + 1 * (TT * HH) + k;
        const float* w2 = W_fc + 2 * (TT * HH) + k;
        const float* w3 = W_fc + 3 * (TT * HH) + k;
        float4 v0a = *(const float4*)w0, v0b = *(const float4*)(w0 + 4);
        float4 v1a = *(const float4*)w1, v1b = *(const float4*)(w1 + 4);
        float4 v2a = *(const float4*)w2, v2b = *(const float4*)(w2 + 4);
        float4 v3a = *(const float4*)w3, v3b = *(const float4*)(w3 + 4);

        a0 += hf[0]*v0a.x + hf[1]*v0a.y + hf[2]*v0a.z + hf[3]*v0a.w
            + hf[4]*v0b.x + hf[5]*v0b.y + hf[6]*v0b.z + hf[7]*v0b.w;
        a1 += hf[0]*v1a.x + hf[1]*v1a.y + hf[2]*v1a.z + hf[3]*v1a.w
            + hf[4]*v1b.x + hf[5]*v1b.y + hf[6]*v1b.z + hf[7]*v1b.w;
        a2 += hf[0]*v2a.x + hf[1]*v2a.y + hf[2]*v2a.z + hf[3]*v2a.w
            + hf[4]*v2b.x + hf[5]*v2b.y + hf[6]*v2b.z + hf[7]*v2b.w;
        a3 += hf[0]*v3a.x + hf[1]*v3a.y + hf[2]*v3a.z + hf[3]*v3a.w
            + hf[4]*v3b.x + hf[5]*v3b.y + hf[6]*v3b.z + hf[7]*v3b.w;
    }

    #pragma unroll
    for (int off = 32; off; off >>= 1) {
        a0 += __shfl_down(a0, off);
        a1 += __shfl_down(a1, off);
        a2 += __shfl_down(a2, off);
        a3 += __shfl_down(a3, off);
    }
    if (lane == 0) {
        float l0 = a0 + b_fc[0], l1 = a1 + b_fc[1];
        float l2 = a2 + b_fc[2], l3 = a3 + b_fc[3];
        float m  = fmaxf(fmaxf(l0, l1), fmaxf(l2, l3));
        float e0 = __expf(l0 - m), e1 = __expf(l1 - m);
        float e2 = __expf(l2 - m), e3 = __expf(l3 - m);
        float s  = e0 + e1 + e2 + e3;
        float4 o; o.x = e0 / s; o.y = e1 / s; o.z = e2 / s; o.w = e3 / s;
        *(float4*)(out + r * NCLS) = o;
    }
}

extern "C" void kernel_launch(void* const* d_in, const int* in_sizes, int n_in,
                              void* d_out, int out_size, void* d_ws, size_t ws_size,
                              hipStream_t stream) {
    const float* x    = (const float*)d_in[0];
    const float* W_ih = (const float*)d_in[1];
    const float* W_hh = (const float*)d_in[2];
    const float* b_ih = (const float*)d_in[3];
    const float* b_hh = (const float*)d_in[4];
    const float* W_fc = (const float*)d_in[5];
    const float* b_fc = (const float*)d_in[6];
    float* out = (float*)d_out;
    f16*  hglob = (f16*)d_ws;        // needs 512*64000*2 = 65.54 MB

    lstm_mfma1<<<BB, 64, 0, stream>>>(x, W_ih, W_hh, b_ih, b_hh, hglob);
    fc_softmax<<<BB / 4, 256, 0, stream>>>(hglob, W_fc, b_fc, out);
}